// Round 4
// baseline (638.585 us; speedup 1.0000x reference)
//
#include <hip/hip_runtime.h>
#include <math.h>

#define BB 128
#define HH 8
#define DD 256
#define MM 8192
#define BH (BB*HH)   // 1024
#define RANK 16

typedef __attribute__((ext_vector_type(8))) short bf16x8;
typedef __attribute__((ext_vector_type(4))) float f32x4;

__device__ inline unsigned short f2bf(float f) {
  unsigned x = __float_as_uint(f);
  unsigned r = x + 0x7FFFu + ((x >> 16) & 1u);
  return (unsigned short)(r >> 16);
}
__device__ inline float bf2f(unsigned short u) {
  return __uint_as_float(((unsigned)u) << 16);
}

// ---------------------------------------------------------------------------
// K1: q[b,h,i] = sum_j probe[h,i,j] * psi[b,j]  (complex)
// ---------------------------------------------------------------------------
__global__ __launch_bounds__(256) void k_q(
    const float* __restrict__ psi, const float* __restrict__ probe_r,
    const float* __restrict__ probe_i, float* __restrict__ qr, float* __restrict__ qi) {
  __shared__ float2 ps0[DD];
  __shared__ float2 ps1[DD];
  int b0 = blockIdx.x * 2;
  int h  = blockIdx.y;
  int i  = threadIdx.x;
  ps0[i] = ((const float2*)psi)[(size_t)b0 * DD + i];
  ps1[i] = ((const float2*)psi)[(size_t)(b0 + 1) * DD + i];
  __syncthreads();
  const float* rr = probe_r + ((size_t)h * DD + i) * DD;
  const float* ri = probe_i + ((size_t)h * DD + i) * DD;
  float a0r = 0.f, a0i = 0.f, a1r = 0.f, a1i = 0.f;
  for (int j = 0; j < DD; j += 4) {
    float4 xr = *(const float4*)(rr + j);
    float4 xi = *(const float4*)(ri + j);
    float2 p0 = ps0[j+0], p1 = ps0[j+1], p2 = ps0[j+2], p3 = ps0[j+3];
    a0r += xr.x*p0.x - xi.x*p0.y;  a0i += xr.x*p0.y + xi.x*p0.x;
    a0r += xr.y*p1.x - xi.y*p1.y;  a0i += xr.y*p1.y + xi.y*p1.x;
    a0r += xr.z*p2.x - xi.z*p2.y;  a0i += xr.z*p2.y + xi.z*p2.x;
    a0r += xr.w*p3.x - xi.w*p3.y;  a0i += xr.w*p3.y + xi.w*p3.x;
    float2 s0 = ps1[j+0], s1 = ps1[j+1], s2 = ps1[j+2], s3 = ps1[j+3];
    a1r += xr.x*s0.x - xi.x*s0.y;  a1i += xr.x*s0.y + xi.x*s0.x;
    a1r += xr.y*s1.x - xi.y*s1.y;  a1i += xr.y*s1.y + xi.y*s1.x;
    a1r += xr.z*s2.x - xi.z*s2.y;  a1i += xr.z*s2.y + xi.z*s2.x;
    a1r += xr.w*s3.x - xi.w*s3.y;  a1i += xr.w*s3.y + xi.w*s3.x;
  }
  size_t o0 = ((size_t)(b0    ) * HH + h) * DD + i;
  size_t o1 = ((size_t)(b0 + 1) * HH + h) * DD + i;
  qr[o0] = a0r; qi[o0] = a0i;
  qr[o1] = a1r; qi[o1] = a1i;
}

// ---------------------------------------------------------------------------
// K2: inv_nrm / fac per row m
// ---------------------------------------------------------------------------
__global__ __launch_bounds__(256) void k_norm(
    const float* __restrict__ u_r, const float* __restrict__ u_i,
    const float* __restrict__ s_logit, float* __restrict__ inv_nrm,
    float* __restrict__ fac) {
  int m = blockIdx.x * 4 + (threadIdx.x >> 6);
  int lane = threadIdx.x & 63;
  const float4* a = (const float4*)(u_r + (size_t)m * DD);
  const float4* b = (const float4*)(u_i + (size_t)m * DD);
  float4 x = a[lane], y = b[lane];
  float s = x.x*x.x + x.y*x.y + x.z*x.z + x.w*x.w
          + y.x*y.x + y.y*y.y + y.z*y.z + y.w*y.w;
  for (int off = 32; off; off >>= 1) s += __shfl_down(s, off);
  if (lane == 0) {
    float inv = 1.0f / sqrtf(fmaxf(s, 1e-8f));
    inv_nrm[m] = inv;
    float sig = 1.0f / (1.0f + expf(-s_logit[m]));
    fac[m] = sig * inv * inv;
  }
}

// ---------------------------------------------------------------------------
// K3a: build A'' (2048 x 1024 bf16) from q.
// row 2bh:   [qr_hi | qi_hi |  qr_lo |  qi_lo]
// row 2bh+1: [qi_hi | -qr_hi | qi_lo | -qr_lo]
// ---------------------------------------------------------------------------
__global__ __launch_bounds__(256) void k_convA(
    const float* __restrict__ qr, const float* __restrict__ qi,
    unsigned short* __restrict__ Ap) {
  int bh = blockIdx.x, d = threadIdx.x;
  float xr = qr[(size_t)bh*DD + d], xi = qi[(size_t)bh*DD + d];
  unsigned short hr = f2bf(xr), hi_ = f2bf(xi);
  unsigned short lr = f2bf(xr - bf2f(hr)), li = f2bf(xi - bf2f(hi_));
  unsigned short* r0 = Ap + (size_t)(2*bh) * 1024;
  unsigned short* r1 = r0 + 1024;
  r0[d] = hr;  r0[256+d] = hi_;            r0[512+d] = lr;  r0[768+d] = li;
  r1[d] = hi_; r1[256+d] = hr ^ 0x8000u;   r1[512+d] = li;  r1[768+d] = lr ^ 0x8000u;
}

// ---------------------------------------------------------------------------
// K3b: build B'' (8192 x 1024 bf16) from u: [ur_hi | ui_hi | ur_lo | ui_lo]
// ---------------------------------------------------------------------------
__global__ __launch_bounds__(256) void k_convB(
    const float* __restrict__ u_r, const float* __restrict__ u_i,
    unsigned short* __restrict__ Bp) {
  int m = blockIdx.x, d = threadIdx.x;
  float xr = u_r[(size_t)m*DD + d], xi = u_i[(size_t)m*DD + d];
  unsigned short hr = f2bf(xr), hi_ = f2bf(xi);
  unsigned short lr = f2bf(xr - bf2f(hr)), li = f2bf(xi - bf2f(hi_));
  unsigned short* r = Bp + (size_t)m * 1024;
  r[d] = hr; r[256+d] = hi_; r[512+d] = lr; r[768+d] = li;
}

// ---------------------------------------------------------------------------
// K4: bf16 MFMA GEMM over virtual K=1536 (hi*hi, hi*lo, lo*hi folded into K).
// Tile 128(A-rows) x 128(m), BK=64, 4 waves (2x2), 4x4 16x16x32 frags/wave.
// Epilogue: scores -> LDS tile (pitch 136) -> coalesced int4 global writes.
// ---------------------------------------------------------------------------
__global__ __launch_bounds__(256, 2) void k_gemm(
    const unsigned short* __restrict__ Ap,   // 2048 x 1024
    const unsigned short* __restrict__ Bp,   // 8192 x 1024
    const float* __restrict__ fac,           // 8192
    unsigned short* __restrict__ sc,         // 1024 x 4096 (bf16)
    int m_off) {
  __shared__ __align__(16) unsigned short SMEM[16384];   // 32 KB
  unsigned short* As = SMEM;          // 128 x 64
  unsigned short* Bs = SMEM + 8192;   // 128 x 64
  int tid  = threadIdx.x;
  int lane = tid & 63, wid = tid >> 6;
  int wm = wid >> 1, wn = wid & 1;
  int a_row0 = blockIdx.y * 128;            // A'' row tile base
  int b_row0 = m_off + blockIdx.x * 128;    // global m tile base

  // staging map: thread t, chunk i: row = (t>>3) + 32*i, kc = t&7 (16B chunks)
  int st_r0 = tid >> 3;
  int st_kc = tid & 7;
  int st_r7 = st_r0 & 7;
  int st_slot = (st_kc ^ st_r7) * 16;

  // frag-read map
  int arow = lane & 15;
  int fr_g = lane >> 4;
  int r7   = lane & 7;
  const char* Abase = (const char*)As + (wm*64 + arow) * 128;
  const char* Bbase = (const char*)Bs + (wn*64 + arow) * 128;

  f32x4 acc[4][4];
#pragma unroll
  for (int i = 0; i < 4; ++i)
#pragma unroll
    for (int j = 0; j < 4; ++j) acc[i][j] = (f32x4){0.f,0.f,0.f,0.f};

  int4 ra[4], rb[4];
  {
    const unsigned short* pa = Ap + (size_t)(a_row0 + st_r0)*1024 + 8*st_kc;
    const unsigned short* pb = Bp + (size_t)(b_row0 + st_r0)*1024 + 8*st_kc;
#pragma unroll
    for (int i = 0; i < 4; ++i) {
      ra[i] = *(const int4*)(pa + (size_t)i*32*1024);
      rb[i] = *(const int4*)(pb + (size_t)i*32*1024);
    }
  }
  const int NT = 24;    // 1536 / 64
  for (int t = 0; t < NT; ++t) {
    __syncthreads();
#pragma unroll
    for (int i = 0; i < 4; ++i) {
      *(int4*)((char*)As + (st_r0 + 32*i)*128 + st_slot) = ra[i];
      *(int4*)((char*)Bs + (st_r0 + 32*i)*128 + st_slot) = rb[i];
    }
    __syncthreads();
    if (t + 1 < NT) {
      int k0 = (t + 1) * 64;
      int ka = (k0 < 512)  ? k0 : k0 - 512;   // A'' segment remap
      int kb = (k0 < 1024) ? k0 : k0 - 1024;  // B'' segment remap
      const unsigned short* pa = Ap + (size_t)(a_row0 + st_r0)*1024 + ka + 8*st_kc;
      const unsigned short* pb = Bp + (size_t)(b_row0 + st_r0)*1024 + kb + 8*st_kc;
#pragma unroll
      for (int i = 0; i < 4; ++i) {
        ra[i] = *(const int4*)(pa + (size_t)i*32*1024);
        rb[i] = *(const int4*)(pb + (size_t)i*32*1024);
      }
    }
#pragma unroll
    for (int ks = 0; ks < 2; ++ks) {
      int slot = ((ks*4 + fr_g) ^ r7) * 16;
      bf16x8 a[4], b[4];
#pragma unroll
      for (int fm = 0; fm < 4; ++fm) a[fm] = *(const bf16x8*)(Abase + fm*2048 + slot);
#pragma unroll
      for (int fn = 0; fn < 4; ++fn) b[fn] = *(const bf16x8*)(Bbase + fn*2048 + slot);
#pragma unroll
      for (int fm = 0; fm < 4; ++fm)
#pragma unroll
        for (int fn = 0; fn < 4; ++fn)
          acc[fm][fn] = __builtin_amdgcn_mfma_f32_16x16x32_bf16(a[fm], b[fn], acc[fm][fn], 0, 0, 0);
    }
  }
  // ---- epilogue: scores -> LDS (64 x 128, pitch 136) -> coalesced writes ----
  __syncthreads();   // all waves done with As/Bs
  const int LP = 136;
  int lr0 = wm*32 + 2*(lane >> 4);
  int lc0 = wn*64 + (lane & 15);
  float fv[4];
#pragma unroll
  for (int fn = 0; fn < 4; ++fn)
    fv[fn] = fac[m_off + blockIdx.x*128 + lc0 + fn*16];
#pragma unroll
  for (int fm = 0; fm < 4; ++fm) {
#pragma unroll
    for (int fn = 0; fn < 4; ++fn) {
      f32x4 c = acc[fm][fn];
      float s0 = fv[fn]*(c.x*c.x + c.y*c.y);
      float s1 = fv[fn]*(c.z*c.z + c.w*c.w);
      SMEM[(lr0 + fm*8    ) * LP + lc0 + fn*16] = f2bf(s0);
      SMEM[(lr0 + fm*8 + 1) * LP + lc0 + fn*16] = f2bf(s1);
    }
  }
  __syncthreads();
  {
    int row = tid >> 2;          // 0..63
    int seg = tid & 3;           // 64 B contiguous per thread
    unsigned short* dst = sc + (size_t)(blockIdx.y*64 + row) * 4096
                             + blockIdx.x*128 + seg*32;
    const unsigned short* src = SMEM + row*LP + seg*32;
#pragma unroll
    for (int c4 = 0; c4 < 4; ++c4)
      *(int4*)(dst + c4*8) = *(const int4*)(src + c4*8);
  }
}

// ---------------------------------------------------------------------------
// K5: per-(bh) top-32 candidates within a 4096-column half of coarse scores.
// ---------------------------------------------------------------------------
__global__ __launch_bounds__(256) void k_top32(
    const unsigned short* __restrict__ sc, int* __restrict__ cand,
    int m_off, int slot_off) {
  __shared__ unsigned long long wtop[128];
  int bh = blockIdx.x, tid = threadIdx.x, lane = tid & 63, w = tid >> 6;
  const unsigned short* row = sc + (size_t)bh * 4096;
  unsigned long long v[16];
#pragma unroll
  for (int j = 0; j < 16; ++j) {
    int idx = j*256 + tid;
    unsigned bits = ((unsigned)row[idx]) << 16;
    v[j] = (((unsigned long long)bits) << 32) | (unsigned)(4095 - idx);
  }
  for (int r = 0; r < 32; ++r) {
    unsigned long long bk = v[0]; int bj = 0;
#pragma unroll
    for (int j = 1; j < 16; ++j) if (v[j] > bk) { bk = v[j]; bj = j; }
    unsigned long long mx = bk;
    for (int off = 32; off; off >>= 1) {
      unsigned long long o = __shfl_xor(mx, off);
      if (o > mx) mx = o;
    }
    if (bk == mx && mx != 0ull) {
#pragma unroll
      for (int j = 0; j < 16; ++j) if (j == bj) v[j] = 0ull;
    }
    if (lane == 0) wtop[w*32 + r] = mx;
  }
  __syncthreads();
  if (w == 0) {
    unsigned long long a = wtop[lane], b = wtop[64 + lane];
    for (int r = 0; r < 32; ++r) {
      unsigned long long bk = (a > b) ? a : b;
      int which = (a > b) ? 0 : 1;
      unsigned long long mx = bk;
      for (int off = 32; off; off >>= 1) {
        unsigned long long o = __shfl_xor(mx, off);
        if (o > mx) mx = o;
      }
      if (bk == mx && mx != 0ull) { if (which == 0) a = 0ull; else b = 0ull; }
      if (lane == 0) {
        int idx = 4095 - (int)(mx & 0xFFFFFFFFull);
        cand[bh*64 + slot_off + r] = m_off + idx;
      }
    }
  }
}

// ---------------------------------------------------------------------------
// K6: exact fp32 rescore of the 64 candidates; top-16 with lax tie order.
// ---------------------------------------------------------------------------
__global__ __launch_bounds__(256) void k_exact(
    const float* __restrict__ qr, const float* __restrict__ qi,
    const float* __restrict__ u_r, const float* __restrict__ u_i,
    const float* __restrict__ fac, const int* __restrict__ cand,
    float* __restrict__ topv, int* __restrict__ topi) {
  __shared__ float qrs[DD], qis[DD];
  __shared__ unsigned long long keys[64];
  int bh = blockIdx.x, tid = threadIdx.x, lane = tid & 63, w = tid >> 6;
  qrs[tid] = qr[(size_t)bh*DD + tid];
  qis[tid] = qi[(size_t)bh*DD + tid];
  __syncthreads();
  float4 xr = *(const float4*)&qrs[lane*4];
  float4 xi = *(const float4*)&qis[lane*4];
  for (int c = 0; c < 16; ++c) {
    int ci = w*16 + c;
    int m = cand[bh*64 + ci];
    float4 a = *(const float4*)(u_r + (size_t)m*DD + lane*4);
    float4 b = *(const float4*)(u_i + (size_t)m*DD + lane*4);
    float pr = a.x*xr.x + a.y*xr.y + a.z*xr.z + a.w*xr.w
             + b.x*xi.x + b.y*xi.y + b.z*xi.z + b.w*xi.w;
    float pi2 = a.x*xi.x + a.y*xi.y + a.z*xi.z + a.w*xi.w
              - (b.x*xr.x + b.y*xr.y + b.z*xr.z + b.w*xr.w);
    for (int off = 32; off; off >>= 1) {
      pr  += __shfl_down(pr, off);
      pi2 += __shfl_down(pi2, off);
    }
    if (lane == 0) {
      float s = fac[m] * (pr*pr + pi2*pi2);
      keys[ci] = (((unsigned long long)__float_as_uint(s)) << 32)
               | (unsigned)(MM - 1 - m);
    }
  }
  __syncthreads();
  if (w == 0) {
    unsigned long long k = keys[lane];
    for (int r = 0; r < 16; ++r) {
      unsigned long long mx = k;
      for (int off = 32; off; off >>= 1) {
        unsigned long long o = __shfl_xor(mx, off);
        if (o > mx) mx = o;
      }
      if (k == mx && mx != 0ull) k = 0ull;
      if (lane == 0) {
        topv[bh*16 + r] = __uint_as_float((unsigned)(mx >> 32));
        topi[bh*16 + r] = MM - 1 - (int)(mx & 0xFFFFFFFFull);
      }
    }
  }
}

// ---------------------------------------------------------------------------
// K7: Householder QR (clarfg convention) + in-place zung2r + diag + outputs.
// ---------------------------------------------------------------------------
__global__ __launch_bounds__(256) void k_qr(
    const float* __restrict__ u_r, const float* __restrict__ u_i,
    const float* __restrict__ inv_nrm,
    const float* __restrict__ w_r, const float* __restrict__ w_i,
    const float* __restrict__ topv, const int* __restrict__ topi,
    float* __restrict__ out) {
  __shared__ float Ar[DD][17];
  __shared__ float Ai[DD][17];
  __shared__ float pwR[16][16], pwI[16][16];
  __shared__ float wvR[16], wvI[16];
  __shared__ float redS[4];
  __shared__ int   idxs[16];
  __shared__ float fA[16], fW[16];
  __shared__ float tauR[16], tauI[16];
  __shared__ float dgR[16], dgI[16];

  int bh = blockIdx.x;
  int tid = threadIdx.x;
  int d = tid;
  if (tid < 16) {
    int id = topi[bh*16 + tid];
    idxs[tid] = id;
    float w = sqrtf(fmaxf(topv[bh*16 + tid], 0.f));
    fW[tid] = w;
    fA[tid] = w * inv_nrm[id];
  }
  __syncthreads();
  for (int j = 0; j < 16; ++j) {
    float f = fA[j];
    size_t base = (size_t)idxs[j] * DD + d;
    Ar[d][j] = u_r[base] * f;
    Ai[d][j] = u_i[base] * f;
  }
  __syncthreads();

  // Phase A: factorize
  for (int j = 0; j < 16; ++j) {
    float ar = Ar[d][j], ai = Ai[d][j];
    float xn2 = (d > j) ? (ar*ar + ai*ai) : 0.f;
    for (int off = 32; off; off >>= 1) xn2 += __shfl_down(xn2, off);
    int lane = tid & 63, wv_ = tid >> 6;
    if (lane == 0) redS[wv_] = xn2;
    __syncthreads();
    xn2 = redS[0] + redS[1] + redS[2] + redS[3];
    float alr = Ar[j][j], ali = Ai[j][j];
    float taur, taui, scr, sci;
    if (xn2 == 0.f && ali == 0.f) {
      taur = 0.f; taui = 0.f; scr = 0.f; sci = 0.f;
    } else {
      float nrm  = sqrtf(alr*alr + ali*ali + xn2);
      float beta = (alr >= 0.f) ? -nrm : nrm;
      taur = (beta - alr) / beta;
      taui = -ali / beta;
      float dr = alr - beta, di = ali;
      float den = dr*dr + di*di;
      scr = dr / den; sci = -di / den;
    }
    __syncthreads();
    if (d > j) {
      float vr = ar*scr - ai*sci;
      float vi = ar*sci + ai*scr;
      Ar[d][j] = vr; Ai[d][j] = vi;
    } else if (d == j) {
      Ar[d][j] = 1.f; Ai[d][j] = 0.f;
      tauR[j] = taur; tauI[j] = taui;
    }
    __syncthreads();
    int c16 = tid & 15, seg = tid >> 4;
    float wr = 0.f, wi = 0.f;
    if (c16 > j) {
      for (int i2 = 0; i2 < 16; ++i2) {
        int dd = seg*16 + i2;
        if (dd >= j) {
          float vr = Ar[dd][j], vi = Ai[dd][j];
          float br = Ar[dd][c16], bi = Ai[dd][c16];
          wr += vr*br + vi*bi;
          wi += vr*bi - vi*br;
        }
      }
    }
    pwR[seg][c16] = wr; pwI[seg][c16] = wi;
    __syncthreads();
    if (tid < 16) {
      float swr = 0.f, swi = 0.f;
      for (int s = 0; s < 16; ++s) { swr += pwR[s][tid]; swi += pwI[s][tid]; }
      wvR[tid] = swr; wvI[tid] = swi;
    }
    __syncthreads();
    if (d >= j) {
      float vr = Ar[d][j], vi = Ai[d][j];
      float tr = taur*vr + taui*vi;
      float ti = taur*vi - taui*vr;
      for (int cc = j+1; cc < 16; ++cc) {
        float wr2 = wvR[cc], wi2 = wvI[cc];
        Ar[d][cc] -= tr*wr2 - ti*wi2;
        Ai[d][cc] -= tr*wi2 + ti*wr2;
      }
    }
    __syncthreads();
  }

  // Phase B: zung2r in place
  for (int i = 15; i >= 0; --i) {
    float tr = tauR[i], ti = tauI[i];
    int c16 = tid & 15, seg = tid >> 4;
    float wr = 0.f, wi = 0.f;
    if (c16 > i) {
      for (int i2 = 0; i2 < 16; ++i2) {
        int dd = seg*16 + i2;
        if (dd >= i) {
          float vr = Ar[dd][i], vi = Ai[dd][i];
          float br = Ar[dd][c16], bi = Ai[dd][c16];
          wr += vr*br + vi*bi;
          wi += vr*bi - vi*br;
        }
      }
    }
    pwR[seg][c16] = wr; pwI[seg][c16] = wi;
    __syncthreads();
    if (tid < 16) {
      float swr = 0.f, swi = 0.f;
      for (int s = 0; s < 16; ++s) { swr += pwR[s][tid]; swi += pwI[s][tid]; }
      wvR[tid] = swr; wvI[tid] = swi;
    }
    __syncthreads();
    float vr = Ar[d][i], vi = Ai[d][i];
    if (d >= i) {
      float tvr = tr*vr - ti*vi;
      float tvi = tr*vi + ti*vr;
      for (int cc = i+1; cc < 16; ++cc) {
        Ar[d][cc] -= tvr*wvR[cc] - tvi*wvI[cc];
        Ai[d][cc] -= tvr*wvI[cc] + tvi*wvR[cc];
      }
      if (d > i) {
        Ar[d][i] = -(tr*vr - ti*vi);
        Ai[d][i] = -(tr*vi + ti*vr);
      } else {
        Ar[d][i] = 1.f - tr;
        Ai[d][i] = -ti;
      }
    } else {
      Ar[d][i] = 0.f;
      Ai[d][i] = 0.f;
    }
    __syncthreads();
  }

  // diag + outputs
  {
    int r16 = tid & 15, seg = tid >> 4;
    float fr = fW[r16];
    size_t rowb = (size_t)idxs[r16] * DD + seg*16;
    float sr = 0.f, si = 0.f;
    for (int i2 = 0; i2 < 16; ++i2) {
      int dd = seg*16 + i2;
      float wr2 = w_r[rowb + i2] * fr;
      float wi2 = w_i[rowb + i2] * fr;
      float qr2 = Ar[dd][r16], qi2 = Ai[dd][r16];
      sr += qr2*wr2 + qi2*wi2;
      si += qr2*wi2 - qi2*wr2;
    }
    pwR[seg][r16] = sr; pwI[seg][r16] = si;
  }
  __syncthreads();
  if (tid < 16) {
    float sr = 0.f, si = 0.f;
    for (int s = 0; s < 16; ++s) { sr += pwR[s][tid]; si += pwI[s][tid]; }
    dgR[tid] = sr; dgI[tid] = si;
  }
  __syncthreads();
  size_t baseU = ((size_t)bh * DD + d) * 32;
  size_t baseV = (size_t)BH * DD * 32 + baseU;
  float4* oU = (float4*)(out + baseU);
  float4* oV = (float4*)(out + baseV);
#pragma unroll
  for (int r = 0; r < 16; r += 2) {
    float q0r = Ar[d][r],   q0i = Ai[d][r];
    float q1r = Ar[d][r+1], q1i = Ai[d][r+1];
    oU[r >> 1] = make_float4(q0r, q0i, q1r, q1i);
    float v0r = q0r*dgR[r]   - q0i*dgI[r];
    float v0i = q0r*dgI[r]   + q0i*dgR[r];
    float v1r = q1r*dgR[r+1] - q1i*dgI[r+1];
    float v1i = q1r*dgI[r+1] + q1i*dgR[r+1];
    oV[r >> 1] = make_float4(v0r, v0i, v1r, v1i);
  }
}

// ---------------------------------------------------------------------------
extern "C" void kernel_launch(void* const* d_in, const int* in_sizes, int n_in,
                              void* d_out, int out_size, void* d_ws, size_t ws_size,
                              hipStream_t stream) {
  (void)in_sizes; (void)n_in; (void)out_size; (void)ws_size;
  const float* psi     = (const float*)d_in[0];
  const float* u_r     = (const float*)d_in[1];
  const float* u_i     = (const float*)d_in[2];
  const float* w_r     = (const float*)d_in[3];
  const float* w_i     = (const float*)d_in[4];
  const float* s_logit = (const float*)d_in[5];
  const float* probe_r = (const float*)d_in[6];
  const float* probe_i = (const float*)d_in[7];

  float* ws = (float*)d_ws;
  float*          qr      = ws;                          // 262144
  float*          qi      = ws + 262144;                 // 262144
  float*          inv_nrm = ws + 524288;                 // 8192
  float*          fac     = ws + 532480;                 // 8192
  float*          topv    = ws + 540672;                 // 16384
  int*            topi    = (int*)(ws + 557056);         // 16384
  int*            cand    = (int*)(ws + 573440);         // 65536
  unsigned short* Ap      = (unsigned short*)(ws + 638976);   // 2048*1024 bf16
  unsigned short* Bp      = (unsigned short*)(ws + 1687552);  // 8192*1024 bf16
  unsigned short* sc      = (unsigned short*)(ws + 5881856);  // 1024*4096 bf16
  float* out = (float*)d_out;

  hipLaunchKernelGGL(k_q,     dim3(BB/2, HH), dim3(256), 0, stream,
                     psi, probe_r, probe_i, qr, qi);
  hipLaunchKernelGGL(k_norm,  dim3(MM/4),     dim3(256), 0, stream,
                     u_r, u_i, s_logit, inv_nrm, fac);
  hipLaunchKernelGGL(k_convA, dim3(BH),       dim3(256), 0, stream, qr, qi, Ap);
  hipLaunchKernelGGL(k_convB, dim3(MM),       dim3(256), 0, stream, u_r, u_i, Bp);
  for (int p = 0; p < 2; ++p) {
    hipLaunchKernelGGL(k_gemm,  dim3(32, 16), dim3(256), 0, stream,
                       Ap, Bp, fac, sc, p*4096);
    hipLaunchKernelGGL(k_top32, dim3(BH),     dim3(256), 0, stream,
                       sc, cand, p*4096, p*32);
  }
  hipLaunchKernelGGL(k_exact, dim3(BH),       dim3(256), 0, stream,
                     qr, qi, u_r, u_i, fac, cand, topv, topi);
  hipLaunchKernelGGL(k_qr,    dim3(BH),       dim3(256), 0, stream,
                     u_r, u_i, inv_nrm, w_r, w_i, topv, topi, out);
}

// Round 5
// 448.299 us; speedup vs baseline: 1.4245x; 1.4245x over previous
//
#include <hip/hip_runtime.h>
#include <math.h>

#define BB 128
#define HH 8
#define DD 256
#define MM 8192
#define BH (BB*HH)   // 1024
#define RANK 16

typedef __attribute__((ext_vector_type(8))) short bf16x8;
typedef __attribute__((ext_vector_type(4))) float f32x4;

__device__ inline unsigned short f2bf(float f) {
  unsigned x = __float_as_uint(f);
  unsigned r = x + 0x7FFFu + ((x >> 16) & 1u);
  return (unsigned short)(r >> 16);
}
__device__ inline float bf2f(unsigned short u) {
  return __uint_as_float(((unsigned)u) << 16);
}

// ---------------------------------------------------------------------------
// K1: q[b,h,i] = sum_j probe[h,i,j] * psi[b,j]  (complex)
// ---------------------------------------------------------------------------
__global__ __launch_bounds__(256) void k_q(
    const float* __restrict__ psi, const float* __restrict__ probe_r,
    const float* __restrict__ probe_i, float* __restrict__ qr, float* __restrict__ qi) {
  __shared__ float2 ps0[DD];
  __shared__ float2 ps1[DD];
  int b0 = blockIdx.x * 2;
  int h  = blockIdx.y;
  int i  = threadIdx.x;
  ps0[i] = ((const float2*)psi)[(size_t)b0 * DD + i];
  ps1[i] = ((const float2*)psi)[(size_t)(b0 + 1) * DD + i];
  __syncthreads();
  const float* rr = probe_r + ((size_t)h * DD + i) * DD;
  const float* ri = probe_i + ((size_t)h * DD + i) * DD;
  float a0r = 0.f, a0i = 0.f, a1r = 0.f, a1i = 0.f;
  for (int j = 0; j < DD; j += 4) {
    float4 xr = *(const float4*)(rr + j);
    float4 xi = *(const float4*)(ri + j);
    float2 p0 = ps0[j+0], p1 = ps0[j+1], p2 = ps0[j+2], p3 = ps0[j+3];
    a0r += xr.x*p0.x - xi.x*p0.y;  a0i += xr.x*p0.y + xi.x*p0.x;
    a0r += xr.y*p1.x - xi.y*p1.y;  a0i += xr.y*p1.y + xi.y*p1.x;
    a0r += xr.z*p2.x - xi.z*p2.y;  a0i += xr.z*p2.y + xi.z*p2.x;
    a0r += xr.w*p3.x - xi.w*p3.y;  a0i += xr.w*p3.y + xi.w*p3.x;
    float2 s0 = ps1[j+0], s1 = ps1[j+1], s2 = ps1[j+2], s3 = ps1[j+3];
    a1r += xr.x*s0.x - xi.x*s0.y;  a1i += xr.x*s0.y + xi.x*s0.x;
    a1r += xr.y*s1.x - xi.y*s1.y;  a1i += xr.y*s1.y + xi.y*s1.x;
    a1r += xr.z*s2.x - xi.z*s2.y;  a1i += xr.z*s2.y + xi.z*s2.x;
    a1r += xr.w*s3.x - xi.w*s3.y;  a1i += xr.w*s3.y + xi.w*s3.x;
  }
  size_t o0 = ((size_t)(b0    ) * HH + h) * DD + i;
  size_t o1 = ((size_t)(b0 + 1) * HH + h) * DD + i;
  qr[o0] = a0r; qi[o0] = a0i;
  qr[o1] = a1r; qi[o1] = a1i;
}

// ---------------------------------------------------------------------------
// K2: inv_nrm / fac per row m
// ---------------------------------------------------------------------------
__global__ __launch_bounds__(256) void k_norm(
    const float* __restrict__ u_r, const float* __restrict__ u_i,
    const float* __restrict__ s_logit, float* __restrict__ inv_nrm,
    float* __restrict__ fac) {
  int m = blockIdx.x * 4 + (threadIdx.x >> 6);
  int lane = threadIdx.x & 63;
  const float4* a = (const float4*)(u_r + (size_t)m * DD);
  const float4* b = (const float4*)(u_i + (size_t)m * DD);
  float4 x = a[lane], y = b[lane];
  float s = x.x*x.x + x.y*x.y + x.z*x.z + x.w*x.w
          + y.x*y.x + y.y*y.y + y.z*y.z + y.w*y.w;
  for (int off = 32; off; off >>= 1) s += __shfl_down(s, off);
  if (lane == 0) {
    float inv = 1.0f / sqrtf(fmaxf(s, 1e-8f));
    inv_nrm[m] = inv;
    float sig = 1.0f / (1.0f + expf(-s_logit[m]));
    fac[m] = sig * inv * inv;
  }
}

// ---------------------------------------------------------------------------
// K3a: build A'' (2048 x 512 bf16, hi only).
// row 2bh:   [qr_hi | qi_hi]
// row 2bh+1: [qi_hi | -qr_hi]
// ---------------------------------------------------------------------------
__global__ __launch_bounds__(256) void k_convA(
    const float* __restrict__ qr, const float* __restrict__ qi,
    unsigned short* __restrict__ Ap) {
  int bh = blockIdx.x, d = threadIdx.x;
  float xr = qr[(size_t)bh*DD + d], xi = qi[(size_t)bh*DD + d];
  unsigned short hr = f2bf(xr), hi_ = f2bf(xi);
  unsigned short* r0 = Ap + (size_t)(2*bh) * 512;
  unsigned short* r1 = r0 + 512;
  r0[d] = hr;  r0[256+d] = hi_;
  r1[d] = hi_; r1[256+d] = hr ^ 0x8000u;
}

// ---------------------------------------------------------------------------
// K3b: build B'' (8192 x 512 bf16, hi only): [ur_hi | ui_hi]
// ---------------------------------------------------------------------------
__global__ __launch_bounds__(256) void k_convB(
    const float* __restrict__ u_r, const float* __restrict__ u_i,
    unsigned short* __restrict__ Bp) {
  int m = blockIdx.x, d = threadIdx.x;
  unsigned short* r = Bp + (size_t)m * 512;
  r[d]     = f2bf(u_r[(size_t)m*DD + d]);
  r[256+d] = f2bf(u_i[(size_t)m*DD + d]);
}

// ---------------------------------------------------------------------------
// K4: bf16 MFMA GEMM, K=512 (hi*hi coarse scores; exact rescore fixes the rest).
// Tile 128(A-rows) x 128(m), BK=64, 4 waves (2x2), 4x4 16x16x32 frags/wave.
// Single dispatch over M=2048, N=8192. Epilogue: LDS tile -> coalesced writes.
// ---------------------------------------------------------------------------
__global__ __launch_bounds__(256, 4) void k_gemm(
    const unsigned short* __restrict__ Ap,   // 2048 x 512
    const unsigned short* __restrict__ Bp,   // 8192 x 512
    const float* __restrict__ fac,           // 8192
    unsigned short* __restrict__ sc) {       // 1024 x 8192 (bf16)
  __shared__ __align__(16) unsigned short SMEM[16384];   // 32 KB
  unsigned short* As = SMEM;          // 128 x 64
  unsigned short* Bs = SMEM + 8192;   // 128 x 64
  int tid  = threadIdx.x;
  int lane = tid & 63, wid = tid >> 6;
  int wm = wid >> 1, wn = wid & 1;
  int a_row0 = blockIdx.y * 128;
  int b_row0 = blockIdx.x * 128;

  int st_r0 = tid >> 3;
  int st_kc = tid & 7;
  int st_slot = (st_kc ^ (st_r0 & 7)) * 16;

  int arow = lane & 15;
  int fr_g = lane >> 4;
  int r7   = lane & 7;
  const char* Abase = (const char*)As + (wm*64 + arow) * 128;
  const char* Bbase = (const char*)Bs + (wn*64 + arow) * 128;

  f32x4 acc[4][4];
#pragma unroll
  for (int i = 0; i < 4; ++i)
#pragma unroll
    for (int j = 0; j < 4; ++j) acc[i][j] = (f32x4){0.f,0.f,0.f,0.f};

  int4 ra[4], rb[4];
  {
    const unsigned short* pa = Ap + (size_t)(a_row0 + st_r0)*512 + 8*st_kc;
    const unsigned short* pb = Bp + (size_t)(b_row0 + st_r0)*512 + 8*st_kc;
#pragma unroll
    for (int i = 0; i < 4; ++i) {
      ra[i] = *(const int4*)(pa + (size_t)i*32*512);
      rb[i] = *(const int4*)(pb + (size_t)i*32*512);
    }
  }
  const int NT = 8;    // 512 / 64
  for (int t = 0; t < NT; ++t) {
    __syncthreads();
#pragma unroll
    for (int i = 0; i < 4; ++i) {
      *(int4*)((char*)As + (st_r0 + 32*i)*128 + st_slot) = ra[i];
      *(int4*)((char*)Bs + (st_r0 + 32*i)*128 + st_slot) = rb[i];
    }
    __syncthreads();
    if (t + 1 < NT) {
      int k0 = (t + 1) * 64;
      const unsigned short* pa = Ap + (size_t)(a_row0 + st_r0)*512 + k0 + 8*st_kc;
      const unsigned short* pb = Bp + (size_t)(b_row0 + st_r0)*512 + k0 + 8*st_kc;
#pragma unroll
      for (int i = 0; i < 4; ++i) {
        ra[i] = *(const int4*)(pa + (size_t)i*32*512);
        rb[i] = *(const int4*)(pb + (size_t)i*32*512);
      }
    }
#pragma unroll
    for (int ks = 0; ks < 2; ++ks) {
      int slot = ((ks*4 + fr_g) ^ r7) * 16;
      bf16x8 a[4], b[4];
#pragma unroll
      for (int fm = 0; fm < 4; ++fm) a[fm] = *(const bf16x8*)(Abase + fm*2048 + slot);
#pragma unroll
      for (int fn = 0; fn < 4; ++fn) b[fn] = *(const bf16x8*)(Bbase + fn*2048 + slot);
#pragma unroll
      for (int fm = 0; fm < 4; ++fm)
#pragma unroll
        for (int fn = 0; fn < 4; ++fn)
          acc[fm][fn] = __builtin_amdgcn_mfma_f32_16x16x32_bf16(a[fm], b[fn], acc[fm][fn], 0, 0, 0);
    }
  }
  // ---- epilogue: scores -> LDS (64 x 128, pitch 136) -> coalesced writes ----
  __syncthreads();
  const int LP = 136;
  int lr0 = wm*32 + 2*(lane >> 4);
  int lc0 = wn*64 + (lane & 15);
  float fv[4];
#pragma unroll
  for (int fn = 0; fn < 4; ++fn)
    fv[fn] = fac[blockIdx.x*128 + lc0 + fn*16];
#pragma unroll
  for (int fm = 0; fm < 4; ++fm) {
#pragma unroll
    for (int fn = 0; fn < 4; ++fn) {
      f32x4 c = acc[fm][fn];
      float s0 = fv[fn]*(c.x*c.x + c.y*c.y);
      float s1 = fv[fn]*(c.z*c.z + c.w*c.w);
      SMEM[(lr0 + fm*8    ) * LP + lc0 + fn*16] = f2bf(s0);
      SMEM[(lr0 + fm*8 + 1) * LP + lc0 + fn*16] = f2bf(s1);
    }
  }
  __syncthreads();
  {
    int row = tid >> 2;
    int seg = tid & 3;
    unsigned short* dst = sc + (size_t)(blockIdx.y*64 + row) * MM
                             + blockIdx.x*128 + seg*32;
    const unsigned short* src = SMEM + row*LP + seg*32;
#pragma unroll
    for (int c4 = 0; c4 < 4; ++c4)
      *(int4*)(dst + c4*8) = *(const int4*)(src + c4*8);
  }
}

// ---------------------------------------------------------------------------
// K5: per-(bh, half) top-32 candidates from coarse scores. grid (BH, 2).
// ---------------------------------------------------------------------------
__global__ __launch_bounds__(256) void k_top32(
    const unsigned short* __restrict__ sc, int* __restrict__ cand) {
  __shared__ unsigned long long wtop[128];
  int bh = blockIdx.x, half = blockIdx.y;
  int tid = threadIdx.x, lane = tid & 63, w = tid >> 6;
  const unsigned short* row = sc + (size_t)bh * MM + half*4096;
  unsigned long long v[16];
#pragma unroll
  for (int j = 0; j < 16; ++j) {
    int idx = j*256 + tid;
    unsigned bits = ((unsigned)row[idx]) << 16;
    v[j] = (((unsigned long long)bits) << 32) | (unsigned)(4095 - idx);
  }
  for (int r = 0; r < 32; ++r) {
    unsigned long long bk = v[0]; int bj = 0;
#pragma unroll
    for (int j = 1; j < 16; ++j) if (v[j] > bk) { bk = v[j]; bj = j; }
    unsigned long long mx = bk;
    for (int off = 32; off; off >>= 1) {
      unsigned long long o = __shfl_xor(mx, off);
      if (o > mx) mx = o;
    }
    if (bk == mx && mx != 0ull) {
#pragma unroll
      for (int j = 0; j < 16; ++j) if (j == bj) v[j] = 0ull;
    }
    if (lane == 0) wtop[w*32 + r] = mx;
  }
  __syncthreads();
  if (w == 0) {
    unsigned long long a = wtop[lane], b = wtop[64 + lane];
    for (int r = 0; r < 32; ++r) {
      unsigned long long bk = (a > b) ? a : b;
      int which = (a > b) ? 0 : 1;
      unsigned long long mx = bk;
      for (int off = 32; off; off >>= 1) {
        unsigned long long o = __shfl_xor(mx, off);
        if (o > mx) mx = o;
      }
      if (bk == mx && mx != 0ull) { if (which == 0) a = 0ull; else b = 0ull; }
      if (lane == 0) {
        int idx = 4095 - (int)(mx & 0xFFFFFFFFull);
        cand[bh*64 + half*32 + r] = half*4096 + idx;
      }
    }
  }
}

// ---------------------------------------------------------------------------
// K6: exact fp32 rescore of the 64 candidates; top-16 with lax tie order.
// ---------------------------------------------------------------------------
__global__ __launch_bounds__(256) void k_exact(
    const float* __restrict__ qr, const float* __restrict__ qi,
    const float* __restrict__ u_r, const float* __restrict__ u_i,
    const float* __restrict__ fac, const int* __restrict__ cand,
    float* __restrict__ topv, int* __restrict__ topi) {
  __shared__ float qrs[DD], qis[DD];
  __shared__ unsigned long long keys[64];
  int bh = blockIdx.x, tid = threadIdx.x, lane = tid & 63, w = tid >> 6;
  qrs[tid] = qr[(size_t)bh*DD + tid];
  qis[tid] = qi[(size_t)bh*DD + tid];
  __syncthreads();
  float4 xr = *(const float4*)&qrs[lane*4];
  float4 xi = *(const float4*)&qis[lane*4];
  for (int c = 0; c < 16; ++c) {
    int ci = w*16 + c;
    int m = cand[bh*64 + ci];
    float4 a = *(const float4*)(u_r + (size_t)m*DD + lane*4);
    float4 b = *(const float4*)(u_i + (size_t)m*DD + lane*4);
    float pr = a.x*xr.x + a.y*xr.y + a.z*xr.z + a.w*xr.w
             + b.x*xi.x + b.y*xi.y + b.z*xi.z + b.w*xi.w;
    float pi2 = a.x*xi.x + a.y*xi.y + a.z*xi.z + a.w*xi.w
              - (b.x*xr.x + b.y*xr.y + b.z*xr.z + b.w*xr.w);
    for (int off = 32; off; off >>= 1) {
      pr  += __shfl_down(pr, off);
      pi2 += __shfl_down(pi2, off);
    }
    if (lane == 0) {
      float s = fac[m] * (pr*pr + pi2*pi2);
      keys[ci] = (((unsigned long long)__float_as_uint(s)) << 32)
               | (unsigned)(MM - 1 - m);
    }
  }
  __syncthreads();
  if (w == 0) {
    unsigned long long k = keys[lane];
    for (int r = 0; r < 16; ++r) {
      unsigned long long mx = k;
      for (int off = 32; off; off >>= 1) {
        unsigned long long o = __shfl_xor(mx, off);
        if (o > mx) mx = o;
      }
      if (k == mx && mx != 0ull) k = 0ull;
      if (lane == 0) {
        topv[bh*16 + r] = __uint_as_float((unsigned)(mx >> 32));
        topi[bh*16 + r] = MM - 1 - (int)(mx & 0xFFFFFFFFull);
      }
    }
  }
}

// ---------------------------------------------------------------------------
// K7: Householder QR (clarfg convention) + in-place zung2r + diag + outputs.
// ---------------------------------------------------------------------------
__global__ __launch_bounds__(256) void k_qr(
    const float* __restrict__ u_r, const float* __restrict__ u_i,
    const float* __restrict__ inv_nrm,
    const float* __restrict__ w_r, const float* __restrict__ w_i,
    const float* __restrict__ topv, const int* __restrict__ topi,
    float* __restrict__ out) {
  __shared__ float Ar[DD][17];
  __shared__ float Ai[DD][17];
  __shared__ float pwR[16][16], pwI[16][16];
  __shared__ float wvR[16], wvI[16];
  __shared__ float redS[4];
  __shared__ int   idxs[16];
  __shared__ float fA[16], fW[16];
  __shared__ float tauR[16], tauI[16];
  __shared__ float dgR[16], dgI[16];

  int bh = blockIdx.x;
  int tid = threadIdx.x;
  int d = tid;
  if (tid < 16) {
    int id = topi[bh*16 + tid];
    idxs[tid] = id;
    float w = sqrtf(fmaxf(topv[bh*16 + tid], 0.f));
    fW[tid] = w;
    fA[tid] = w * inv_nrm[id];
  }
  __syncthreads();
  for (int j = 0; j < 16; ++j) {
    float f = fA[j];
    size_t base = (size_t)idxs[j] * DD + d;
    Ar[d][j] = u_r[base] * f;
    Ai[d][j] = u_i[base] * f;
  }
  __syncthreads();

  // Phase A: factorize
  for (int j = 0; j < 16; ++j) {
    float ar = Ar[d][j], ai = Ai[d][j];
    float xn2 = (d > j) ? (ar*ar + ai*ai) : 0.f;
    for (int off = 32; off; off >>= 1) xn2 += __shfl_down(xn2, off);
    int lane = tid & 63, wv_ = tid >> 6;
    if (lane == 0) redS[wv_] = xn2;
    __syncthreads();
    xn2 = redS[0] + redS[1] + redS[2] + redS[3];
    float alr = Ar[j][j], ali = Ai[j][j];
    float taur, taui, scr, sci;
    if (xn2 == 0.f && ali == 0.f) {
      taur = 0.f; taui = 0.f; scr = 0.f; sci = 0.f;
    } else {
      float nrm  = sqrtf(alr*alr + ali*ali + xn2);
      float beta = (alr >= 0.f) ? -nrm : nrm;
      taur = (beta - alr) / beta;
      taui = -ali / beta;
      float dr = alr - beta, di = ali;
      float den = dr*dr + di*di;
      scr = dr / den; sci = -di / den;
    }
    __syncthreads();
    if (d > j) {
      float vr = ar*scr - ai*sci;
      float vi = ar*sci + ai*scr;
      Ar[d][j] = vr; Ai[d][j] = vi;
    } else if (d == j) {
      Ar[d][j] = 1.f; Ai[d][j] = 0.f;
      tauR[j] = taur; tauI[j] = taui;
    }
    __syncthreads();
    int c16 = tid & 15, seg = tid >> 4;
    float wr = 0.f, wi = 0.f;
    if (c16 > j) {
      for (int i2 = 0; i2 < 16; ++i2) {
        int dd = seg*16 + i2;
        if (dd >= j) {
          float vr = Ar[dd][j], vi = Ai[dd][j];
          float br = Ar[dd][c16], bi = Ai[dd][c16];
          wr += vr*br + vi*bi;
          wi += vr*bi - vi*br;
        }
      }
    }
    pwR[seg][c16] = wr; pwI[seg][c16] = wi;
    __syncthreads();
    if (tid < 16) {
      float swr = 0.f, swi = 0.f;
      for (int s = 0; s < 16; ++s) { swr += pwR[s][tid]; swi += pwI[s][tid]; }
      wvR[tid] = swr; wvI[tid] = swi;
    }
    __syncthreads();
    if (d >= j) {
      float vr = Ar[d][j], vi = Ai[d][j];
      float tr = taur*vr + taui*vi;
      float ti = taur*vi - taui*vr;
      for (int cc = j+1; cc < 16; ++cc) {
        float wr2 = wvR[cc], wi2 = wvI[cc];
        Ar[d][cc] -= tr*wr2 - ti*wi2;
        Ai[d][cc] -= tr*wi2 + ti*wr2;
      }
    }
    __syncthreads();
  }

  // Phase B: zung2r in place
  for (int i = 15; i >= 0; --i) {
    float tr = tauR[i], ti = tauI[i];
    int c16 = tid & 15, seg = tid >> 4;
    float wr = 0.f, wi = 0.f;
    if (c16 > i) {
      for (int i2 = 0; i2 < 16; ++i2) {
        int dd = seg*16 + i2;
        if (dd >= i) {
          float vr = Ar[dd][i], vi = Ai[dd][i];
          float br = Ar[dd][c16], bi = Ai[dd][c16];
          wr += vr*br + vi*bi;
          wi += vr*bi - vi*br;
        }
      }
    }
    pwR[seg][c16] = wr; pwI[seg][c16] = wi;
    __syncthreads();
    if (tid < 16) {
      float swr = 0.f, swi = 0.f;
      for (int s = 0; s < 16; ++s) { swr += pwR[s][tid]; swi += pwI[s][tid]; }
      wvR[tid] = swr; wvI[tid] = swi;
    }
    __syncthreads();
    float vr = Ar[d][i], vi = Ai[d][i];
    if (d >= i) {
      float tvr = tr*vr - ti*vi;
      float tvi = tr*vi + ti*vr;
      for (int cc = i+1; cc < 16; ++cc) {
        Ar[d][cc] -= tvr*wvR[cc] - tvi*wvI[cc];
        Ai[d][cc] -= tvr*wvI[cc] + tvi*wvR[cc];
      }
      if (d > i) {
        Ar[d][i] = -(tr*vr - ti*vi);
        Ai[d][i] = -(tr*vi + ti*vr);
      } else {
        Ar[d][i] = 1.f - tr;
        Ai[d][i] = -ti;
      }
    } else {
      Ar[d][i] = 0.f;
      Ai[d][i] = 0.f;
    }
    __syncthreads();
  }

  // diag + outputs
  {
    int r16 = tid & 15, seg = tid >> 4;
    float fr = fW[r16];
    size_t rowb = (size_t)idxs[r16] * DD + seg*16;
    float sr = 0.f, si = 0.f;
    for (int i2 = 0; i2 < 16; ++i2) {
      int dd = seg*16 + i2;
      float wr2 = w_r[rowb + i2] * fr;
      float wi2 = w_i[rowb + i2] * fr;
      float qr2 = Ar[dd][r16], qi2 = Ai[dd][r16];
      sr += qr2*wr2 + qi2*wi2;
      si += qr2*wi2 - qi2*wr2;
    }
    pwR[seg][r16] = sr; pwI[seg][r16] = si;
  }
  __syncthreads();
  if (tid < 16) {
    float sr = 0.f, si = 0.f;
    for (int s = 0; s < 16; ++s) { sr += pwR[s][tid]; si += pwI[s][tid]; }
    dgR[tid] = sr; dgI[tid] = si;
  }
  __syncthreads();
  size_t baseU = ((size_t)bh * DD + d) * 32;
  size_t baseV = (size_t)BH * DD * 32 + baseU;
  float4* oU = (float4*)(out + baseU);
  float4* oV = (float4*)(out + baseV);
#pragma unroll
  for (int r = 0; r < 16; r += 2) {
    float q0r = Ar[d][r],   q0i = Ai[d][r];
    float q1r = Ar[d][r+1], q1i = Ai[d][r+1];
    oU[r >> 1] = make_float4(q0r, q0i, q1r, q1i);
    float v0r = q0r*dgR[r]   - q0i*dgI[r];
    float v0i = q0r*dgI[r]   + q0i*dgR[r];
    float v1r = q1r*dgR[r+1] - q1i*dgI[r+1];
    float v1i = q1r*dgI[r+1] + q1i*dgR[r+1];
    oV[r >> 1] = make_float4(v0r, v0i, v1r, v1i);
  }
}

// ---------------------------------------------------------------------------
extern "C" void kernel_launch(void* const* d_in, const int* in_sizes, int n_in,
                              void* d_out, int out_size, void* d_ws, size_t ws_size,
                              hipStream_t stream) {
  (void)in_sizes; (void)n_in; (void)out_size; (void)ws_size;
  const float* psi     = (const float*)d_in[0];
  const float* u_r     = (const float*)d_in[1];
  const float* u_i     = (const float*)d_in[2];
  const float* w_r     = (const float*)d_in[3];
  const float* w_i     = (const float*)d_in[4];
  const float* s_logit = (const float*)d_in[5];
  const float* probe_r = (const float*)d_in[6];
  const float* probe_i = (const float*)d_in[7];

  float* ws = (float*)d_ws;
  float*          qr      = ws;                          // 262144
  float*          qi      = ws + 262144;                 // 262144
  float*          inv_nrm = ws + 524288;                 // 8192
  float*          fac     = ws + 532480;                 // 8192
  float*          topv    = ws + 540672;                 // 16384
  int*            topi    = (int*)(ws + 557056);         // 16384
  int*            cand    = (int*)(ws + 573440);         // 65536 ints
  unsigned short* Ap      = (unsigned short*)(ws + 638976);   // 2048*512 bf16 (2 MB)
  unsigned short* Bp      = (unsigned short*)(ws + 1163264);  // 8192*512 bf16 (8 MB)
  unsigned short* sc      = (unsigned short*)(ws + 3260416);  // 1024*8192 bf16 (16 MB)
  float* out = (float*)d_out;

  hipLaunchKernelGGL(k_q,     dim3(BB/2, HH), dim3(256), 0, stream,
                     psi, probe_r, probe_i, qr, qi);
  hipLaunchKernelGGL(k_norm,  dim3(MM/4),     dim3(256), 0, stream,
                     u_r, u_i, s_logit, inv_nrm, fac);
  hipLaunchKernelGGL(k_convA, dim3(BH),       dim3(256), 0, stream, qr, qi, Ap);
  hipLaunchKernelGGL(k_convB, dim3(MM),       dim3(256), 0, stream, u_r, u_i, Bp);
  hipLaunchKernelGGL(k_gemm,  dim3(64, 16),   dim3(256), 0, stream,
                     Ap, Bp, fac, sc);
  hipLaunchKernelGGL(k_top32, dim3(BH, 2),    dim3(256), 0, stream, sc, cand);
  hipLaunchKernelGGL(k_exact, dim3(BH),       dim3(256), 0, stream,
                     qr, qi, u_r, u_i, fac, cand, topv, topi);
  hipLaunchKernelGGL(k_qr,    dim3(BH),       dim3(256), 0, stream,
                     u_r, u_i, inv_nrm, w_r, w_i, topv, topi, out);
}